// Round 12
// baseline (302.726 us; speedup 1.0000x reference)
//
#include <hip/hip_runtime.h>
#include <hip/hip_bf16.h>
#include <math.h>

#define EPB 64
#define ALPHA 0.17677669529663687f
#define INV_SQRT3 0.57735026918962576f

typedef __attribute__((ext_vector_type(8))) short short8;
typedef __attribute__((ext_vector_type(4))) float f32x4;

__device__ __forceinline__ float silu_f(float x) { return x / (1.0f + __expf(-x)); }

__device__ __forceinline__ unsigned short bf16_rne(float x) {
  unsigned int u = __float_as_uint(x);
  unsigned int r = u + 0x7fffu + ((u >> 16) & 1u);
  return (unsigned short)(r >> 16);
}

__device__ __forceinline__ float bf2f(unsigned short s) {
  return __uint_as_float(((unsigned int)s) << 16);
}

// ---------------------------------------------------------------------------
// Merged prep: blocks 0..15 transpose w2 -> w2t; blocks 16.. CSR count.
// Last-finishing block also performs the exclusive scan (done-counter
// pattern; deg read back with agent-scope atomic loads).
// ---------------------------------------------------------------------------
__global__ __launch_bounds__(256) void prep_kernel(const float* __restrict__ w2,
                                                   unsigned short* __restrict__ w2t,
                                                   const int* __restrict__ eidx,
                                                   int* __restrict__ deg,
                                                   int* __restrict__ done,
                                                   int* __restrict__ rank,
                                                   int* __restrict__ offs,
                                                   int N, int E) {
  __shared__ int sums[256];
  __shared__ int s_last;
  const int t = threadIdx.x;

  if (blockIdx.x < 16) {
    __shared__ unsigned short tile[16][260];
    const int k0 = (blockIdx.x & 3) * 16;
    const int c0 = (blockIdx.x >> 2) * 256;
    #pragma unroll
    for (int j = 0; j < 16; ++j)
      tile[j][t] = bf16_rne(w2[(size_t)(k0 + j) * 1024 + c0 + t]);
    __syncthreads();
    union { unsigned short s[16]; uint4 q[2]; } pk;
    #pragma unroll
    for (int j = 0; j < 16; ++j) pk.s[j] = tile[j][t];
    uint4* dst = (uint4*)&w2t[(size_t)(c0 + t) * 64 + k0];
    dst[0] = pk.q[0];
    dst[1] = pk.q[1];
  } else {
    const int e = (blockIdx.x - 16) * 256 + t;
    if (e < E) rank[e] = atomicAdd(&deg[eidx[E + e]], 1);
  }

  // last-block-done: the final block to finish performs the scan
  __threadfence();
  if (t == 0) {
    const int old = atomicAdd(done, 1);
    s_last = (old == (int)gridDim.x - 1) ? 1 : 0;
  }
  __syncthreads();
  if (s_last) {
    __threadfence();
    const int ch = (N + 255) >> 8;
    const int lo = t * ch;
    const int hi = min(lo + ch, N);
    int s = 0;
    for (int i = lo; i < hi; ++i)
      s += __hip_atomic_load(&deg[i], __ATOMIC_RELAXED, __HIP_MEMORY_SCOPE_AGENT);
    sums[t] = s;
    __syncthreads();
    #pragma unroll
    for (int d = 1; d < 256; d <<= 1) {
      int v = (t >= d) ? sums[t - d] : 0;
      __syncthreads();
      sums[t] += v;
      __syncthreads();
    }
    int run = sums[t] - s;
    for (int i = lo; i < hi; ++i) {
      offs[i] = run;
      run += __hip_atomic_load(&deg[i], __ATOMIC_RELAXED, __HIP_MEMORY_SCOPE_AGENT);
    }
    if (lo < N && hi == N) offs[N] = run;
  }
}

// ---------------------------------------------------------------------------
// Edge kernel: 512 threads = 8 waves; wave = (section, half), 2 M-tiles each.
// Same 38.4 KB LDS as R11 but 2x the waves/CU for latency hiding (R11
// post-mortem: issue-idle ~63%, LDS-occupancy lever dead at 256 threads).
// __launch_bounds__(512,6): VGPR cap 85 (need ~72, no spill), 3 blocks/CU
// -> up to 24 waves/CU.
// ---------------------------------------------------------------------------
__global__ __launch_bounds__(512, 6) void tfn_edge_kernel(
    const float* __restrict__ nf,     // N x 64
    const float* __restrict__ esh,    // E x 4
    const float* __restrict__ emb,    // E x 16
    const float* __restrict__ w1g,    // 16 x 64
    const float* __restrict__ b1g,    // 64
    const unsigned short* __restrict__ w2t, // 1024 x 64 bf16 (transposed)
    const float* __restrict__ b2g,    // 1024
    const int*   __restrict__ eidx,   // 2 x E
    const int*   __restrict__ rank,   // E (posmode)
    const int*   __restrict__ offs,   // N+1 (posmode)
    float* __restrict__ msg,          // E x 64 dst-sorted (posmode)
    float* __restrict__ agg,          // N x 64 pre-zeroed (fallback)
    int E, int posmode)
{
  __shared__ __align__(16) unsigned char smem[38400];
  float* fsT  = (float*)(smem);                            // [16][68] fp32
  float* fbT  = (float*)(smem + 4352);                     // [16][68]
  float* fxvT = (float*)(smem + 8704);                     // 3 planes x [16][68]
  unsigned short* embs = (unsigned short*)(smem + 21760);  // [64][16] bf16
  unsigned short* w1T  = (unsigned short*)(smem + 23808);  // [64][16] bf16 (T)
  unsigned short* t01 = (unsigned short*)(smem);           // overlay: 2 x [64][18]
  unsigned short* t2s = (unsigned short*)(smem + 4608);    // overlay: [64][18]
  unsigned short* t3s = (unsigned short*)(smem + 6912);    // overlay: 3 x [64][18]
  unsigned short* hsm = (unsigned short*)(smem + 25856);   // [64][72] bf16
  unsigned short* b2s = (unsigned short*)(smem + 35072);   // [1024] bf16
  float* shs_l = (float*)(smem + 37120);                   // 64
  float* shv_l = (float*)(smem + 37376);                   // 192
  int*   pos_l = (int*)(smem + 38144);                     // 64

  const int tid = threadIdx.x;
  const int ebase = blockIdx.x * EPB;

  // ---------------- phase 0: stage inputs + factor tables ------------------
  if (tid < 256) {
    const int e = tid >> 2, p = tid & 3;
    int eg = ebase + e; if (eg >= E) eg = E - 1;

    const float4 em = *(const float4*)&emb[(size_t)eg * 16 + p * 4];
    {
      const unsigned int lo = bf16_rne(em.x) | ((unsigned int)bf16_rne(em.y) << 16);
      const unsigned int hi = bf16_rne(em.z) | ((unsigned int)bf16_rne(em.w) << 16);
      *(uint2*)&embs[e * 16 + p * 4] = make_uint2(lo, hi);
    }

    const float4 sh = *(const float4*)&esh[(size_t)eg * 4];
    if (p == 0) {
      shs_l[e] = sh.x;
      shv_l[e * 3 + 0] = sh.y; shv_l[e * 3 + 1] = sh.z; shv_l[e * 3 + 2] = sh.w;
      const int dst = eidx[E + eg];
      pos_l[e] = posmode ? (offs[dst] + rank[eg]) : dst;
    }

    const int src = eidx[eg];
    const float4* row4 = (const float4*)(nf + (size_t)src * 64);
    const float4 xs4 = row4[p];
    const float4 va  = row4[4 + p * 3 + 0];
    const float4 vb  = row4[4 + p * 3 + 1];
    const float4 vc  = row4[4 + p * 3 + 2];
    const float xsr[4] = {xs4.x, xs4.y, xs4.z, xs4.w};
    const float xvf[12] = {va.x, va.y, va.z, va.w, vb.x, vb.y, vb.z, vb.w,
                           vc.x, vc.y, vc.z, vc.w};
    #pragma unroll
    for (int uu = 0; uu < 4; ++uu) {
      const int u = p * 4 + uu;
      const float x0 = xvf[uu * 3 + 0];
      const float x1 = xvf[uu * 3 + 1];
      const float x2 = xvf[uu * 3 + 2];
      fsT[u * 68 + e] = xsr[uu];
      fbT[u * 68 + e] = x0 * sh.y + x1 * sh.z + x2 * sh.w;
      fxvT[0 * 1088 + u * 68 + e] = x0;
      fxvT[1 * 1088 + u * 68 + e] = x1;
      fxvT[2 * 1088 + u * 68 + e] = x2;
    }
  } else {
    const int t2 = tid - 256;
    const int r = t2 >> 4, c4 = (t2 & 15) * 4;
    const float4 wv = *(const float4*)&w1g[r * 64 + c4];
    w1T[(c4 + 0) * 16 + r] = bf16_rne(wv.x);
    w1T[(c4 + 1) * 16 + r] = bf16_rne(wv.y);
    w1T[(c4 + 2) * 16 + r] = bf16_rne(wv.z);
    w1T[(c4 + 3) * 16 + r] = bf16_rne(wv.w);
  }
  {
    const float2 bv = *(const float2*)&b2g[tid * 2];
    *(unsigned int*)&b2s[tid * 2] =
        (unsigned int)bf16_rne(bv.x) | ((unsigned int)bf16_rne(bv.y) << 16);
  }
  __syncthreads();

  const int lane = tid & 63;
  const int wv8  = tid >> 6;           // wave 0..7
  const int sec  = wv8 >> 1;           // W-section 0..3
  const int half = wv8 & 1;            // M-tile half
  const int q = lane >> 4, m = lane & 15;

  union AF { uint4 u4; short8 s8; };

  // ---------------- layer 1 via MFMA: h = silu(emb @ w1 + b1) --------------
  // wave (et = wv8>>1, ct pair = (wv8&1)*2): 2 MFMAs each, 8 waves = 16 tiles
  {
    const int et = sec;
    AF ea;
    if (q < 2) ea.u4 = *(const uint4*)&embs[(et * 16 + m) * 16 + q * 8];
    else       ea.u4 = make_uint4(0, 0, 0, 0);
    #pragma unroll
    for (int j = 0; j < 2; ++j) {
      const int ct = half * 2 + j;
      AF wb;
      if (q < 2) wb.u4 = *(const uint4*)&w1T[(ct * 16 + m) * 16 + q * 8];
      else       wb.u4 = make_uint4(0, 0, 0, 0);
      const float b1v = b1g[ct * 16 + m];
      f32x4 c = {b1v, b1v, b1v, b1v};
      c = __builtin_amdgcn_mfma_f32_16x16x32_bf16(ea.s8, wb.s8, c, 0, 0, 0);
      #pragma unroll
      for (int r = 0; r < 4; ++r)
        hsm[(et * 16 + q * 4 + r) * 72 + ct * 16 + m] = bf16_rne(silu_f(c[r]));
    }
  }
  __syncthreads();

  // ---------------- main loop: wave = (section, half), 2 M-tiles -----------
  AF afr[2][2];
  #pragma unroll
  for (int j = 0; j < 2; ++j)
    #pragma unroll
    for (int ks = 0; ks < 2; ++ks)
      afr[j][ks].u4 = *(const uint4*)&hsm[((half * 2 + j) * 16 + m) * 72 + ks * 32 + q * 8];

  const float* ftab = (sec == 3) ? fbT : fsT;
  const uint4* w2tq = (const uint4*)w2t;
  const uint4* bp = w2tq + ((size_t)(sec * 256 + m)) * 8 + q;

  float accA[2][4] = {};
  float accB[2][4] = {};
  float accC[2][4] = {};

  AF b0v, b1v;
  b0v.u4 = bp[0];
  b1v.u4 = bp[4];

  #pragma unroll 2
  for (int u = 0; u < 16; ++u) {
    AF n0, n1;
    if (u < 15) {
      n0.u4 = bp[(u + 1) * 128];
      n1.u4 = bp[(u + 1) * 128 + 4];
    }
    const float b2v = bf2f(b2s[sec * 256 + u * 16 + m]);

    #pragma unroll
    for (int j = 0; j < 2; ++j) {
      const int mt = half * 2 + j;
      f32x4 c = {b2v, b2v, b2v, b2v};
      c = __builtin_amdgcn_mfma_f32_16x16x32_bf16(afr[j][0].s8, b0v.s8, c, 0, 0, 0);
      c = __builtin_amdgcn_mfma_f32_16x16x32_bf16(afr[j][1].s8, b1v.s8, c, 0, 0, 0);

      const int fo = mt * 16 + q * 4;
      if (sec == 2) {
        const float4 f0 = *(const float4*)&fxvT[0 * 1088 + u * 68 + fo];
        const float4 f1 = *(const float4*)&fxvT[1 * 1088 + u * 68 + fo];
        const float4 f2 = *(const float4*)&fxvT[2 * 1088 + u * 68 + fo];
        const float fA[4] = {f0.x, f0.y, f0.z, f0.w};
        const float fB[4] = {f1.x, f1.y, f1.z, f1.w};
        const float fC[4] = {f2.x, f2.y, f2.z, f2.w};
        #pragma unroll
        for (int r = 0; r < 4; ++r) {
          accA[j][r] = fmaf(fA[r], c[r], accA[j][r]);
          accB[j][r] = fmaf(fB[r], c[r], accB[j][r]);
          accC[j][r] = fmaf(fC[r], c[r], accC[j][r]);
        }
      } else {
        const float4 f = *(const float4*)&ftab[u * 68 + fo];
        const float fA[4] = {f.x, f.y, f.z, f.w};
        #pragma unroll
        for (int r = 0; r < 4; ++r)
          accA[j][r] = fmaf(fA[r], c[r], accA[j][r]);
      }
    }
    if (u < 15) { b0v = n0; b1v = n1; }
  }

  __syncthreads();   // factor tables dead; t-overlay may now be written

  // ---------------- flush wave partials to LDS (bf16, stride 18) -----------
  #pragma unroll
  for (int j = 0; j < 2; ++j)
    #pragma unroll
    for (int r = 0; r < 4; ++r) {
      const int e = (half * 2 + j) * 16 + q * 4 + r;
      if (sec == 0)      t01[e * 18 + m]        = bf16_rne(accA[j][r] * shs_l[e]);
      else if (sec == 1) t2s[e * 18 + m]        = bf16_rne(accA[j][r]);
      else if (sec == 3) t01[1152 + e * 18 + m] = bf16_rne(accA[j][r]);
      else {
        const float s = shs_l[e];
        t3s[0 * 1152 + e * 18 + m] = bf16_rne(accA[j][r] * s);
        t3s[1 * 1152 + e * 18 + m] = bf16_rne(accB[j][r] * s);
        t3s[2 * 1152 + e * 18 + m] = bf16_rne(accC[j][r] * s);
      }
    }
  __syncthreads();

  // ---------------- combine + emit, coalesced per-edge rows ----------------
  {
    const int lc = lane;
    const int cc = lc - 16;
    const int v  = cc / 3;
    const int i3 = cc - v * 3;
    #pragma unroll 1
    for (int t8 = 0; t8 < 8; ++t8) {
      const int e = wv8 * 8 + t8;
      if (ebase + e < E) {
        float val;
        if (lc < 16) {
          val = ALPHA * (bf2f(t01[e * 18 + lc]) + INV_SQRT3 * bf2f(t01[1152 + e * 18 + lc]));
        } else {
          val = ALPHA * (bf2f(t2s[e * 18 + v]) * shv_l[e * 3 + i3] +
                         bf2f(t3s[i3 * 1152 + e * 18 + v]));
        }
        if (posmode) msg[(size_t)pos_l[e] * 64 + lc] = val;
        else         atomicAdd(&agg[(size_t)pos_l[e] * 64 + lc], val);
      }
    }
  }
}

// ---------------------------------------------------------------------------
// Fused aggregation + node transform (R9-proven, unchanged). Block = 4 nodes.
// ---------------------------------------------------------------------------
__global__ __launch_bounds__(256) void tfn_agg_node_kernel(
    const float* __restrict__ msg, const int* __restrict__ offs,
    const float* __restrict__ nf, const float* __restrict__ lw0,
    const float* __restrict__ lw1, float* __restrict__ out, int N)
{
  __shared__ float ag[4 * 68];
  __shared__ float w0s[256], w1s[256];
  const int t = threadIdx.x;
  w0s[t] = lw0[t];
  w1s[t] = lw1[t];

  const int n0 = blockIdx.x * 4;
  {
    const int w = t >> 6, lane = t & 63;
    const int rq = lane >> 4, cl = lane & 15;
    const int n = n0 + w;
    if (n < N) {
      const int s = offs[n], e = offs[n + 1];
      float a0 = 0.0f, a1 = 0.0f, a2 = 0.0f, a3 = 0.0f;
      for (int j = s + rq; j < e; j += 4) {
        const float4 v = *(const float4*)&msg[(size_t)j * 64 + cl * 4];
        a0 += v.x; a1 += v.y; a2 += v.z; a3 += v.w;
      }
      a0 += __shfl_xor(a0, 16); a0 += __shfl_xor(a0, 32);
      a1 += __shfl_xor(a1, 16); a1 += __shfl_xor(a1, 32);
      a2 += __shfl_xor(a2, 16); a2 += __shfl_xor(a2, 32);
      a3 += __shfl_xor(a3, 16); a3 += __shfl_xor(a3, 32);
      if (rq == 0) *(float4*)&ag[w * 68 + cl * 4] = make_float4(a0, a1, a2, a3);
    }
  }
  __syncthreads();
  {
    const int node = t >> 6, c = t & 63;
    const int n = n0 + node;
    if (n >= N) return;
    const float* a = &ag[node * 68];
    float val;
    if (c < 16) {
      float accv = 0.0f;
      #pragma unroll
      for (int u = 0; u < 16; ++u) accv = fmaf(a[u], w0s[u * 16 + c], accv);
      const float ts = 0.25f * accv;
      const float ns = fabsf(ts);
      const float g = (ns / (1.0f + __expf(-ns))) / (ns + 1e-8f);
      val = ts * g;
    } else {
      const int cc = c - 16;
      const int v = cc / 3, i = cc - v * 3;
      float a0 = 0.0f, a1 = 0.0f, a2 = 0.0f;
      #pragma unroll
      for (int u = 0; u < 16; ++u) {
        const float w = w1s[u * 16 + v];
        a0 = fmaf(a[16 + u * 3 + 0], w, a0);
        a1 = fmaf(a[16 + u * 3 + 1], w, a1);
        a2 = fmaf(a[16 + u * 3 + 2], w, a2);
      }
      a0 *= 0.25f; a1 *= 0.25f; a2 *= 0.25f;
      const float nv = sqrtf(a0 * a0 + a1 * a1 + a2 * a2);
      const float g = (nv / (1.0f + __expf(-nv))) / (nv + 1e-8f);
      val = ((i == 0) ? a0 : (i == 1) ? a1 : a2) * g;
    }
    out[(size_t)n * 64 + c] = nf[(size_t)n * 64 + c] + val;
  }
}

// ---------------------------------------------------------------------------
// Fallback node kernel (atomic path only).
// ---------------------------------------------------------------------------
__global__ __launch_bounds__(256) void tfn_node_kernel(
    const float* __restrict__ nf,
    const float* __restrict__ lw0,
    const float* __restrict__ lw1,
    float* __restrict__ out, int N)
{
  __shared__ float w0s[256], w1s[256];
  const int tid = threadIdx.x;
  w0s[tid] = lw0[tid];
  w1s[tid] = lw1[tid];
  __syncthreads();

  const int n = blockIdx.x * 256 + tid;
  if (n >= N) return;

  float* rowp = out + (size_t)n * 64;
  float as[16], av[16][3];
  #pragma unroll
  for (int u = 0; u < 16; ++u) as[u] = rowp[u];
  #pragma unroll
  for (int u = 0; u < 16; ++u) {
    av[u][0] = rowp[16 + u * 3 + 0];
    av[u][1] = rowp[16 + u * 3 + 1];
    av[u][2] = rowp[16 + u * 3 + 2];
  }
  const float* nfr = nf + (size_t)n * 64;
  float res[64];

  #pragma unroll
  for (int v = 0; v < 16; ++v) {
    float acc = 0.0f;
    #pragma unroll
    for (int u = 0; u < 16; ++u) acc = fmaf(as[u], w0s[u * 16 + v], acc);
    const float ts = 0.25f * acc;
    const float ns = fabsf(ts);
    const float g = (ns / (1.0f + __expf(-ns))) / (ns + 1e-8f);
    res[v] = nfr[v] + ts * g;
  }
  #pragma unroll
  for (int v = 0; v < 16; ++v) {
    float a0 = 0.0f, a1 = 0.0f, a2 = 0.0f;
    #pragma unroll
    for (int u = 0; u < 16; ++u) {
      const float w = w1s[u * 16 + v];
      a0 = fmaf(av[u][0], w, a0);
      a1 = fmaf(av[u][1], w, a1);
      a2 = fmaf(av[u][2], w, a2);
    }
    a0 *= 0.25f; a1 *= 0.25f; a2 *= 0.25f;
    const float nv = sqrtf(a0 * a0 + a1 * a1 + a2 * a2);
    const float g = (nv / (1.0f + __expf(-nv))) / (nv + 1e-8f);
    res[16 + v * 3 + 0] = nfr[16 + v * 3 + 0] + a0 * g;
    res[16 + v * 3 + 1] = nfr[16 + v * 3 + 1] + a1 * g;
    res[16 + v * 3 + 2] = nfr[16 + v * 3 + 2] + a2 * g;
  }
  #pragma unroll
  for (int o = 0; o < 64; o += 4) {
    *(float4*)&rowp[o] = make_float4(res[o], res[o + 1], res[o + 2], res[o + 3]);
  }
}

extern "C" void kernel_launch(void* const* d_in, const int* in_sizes, int n_in,
                              void* d_out, int out_size, void* d_ws, size_t ws_size,
                              hipStream_t stream) {
  const float* nf  = (const float*)d_in[0];
  const float* esh = (const float*)d_in[1];
  const float* emb = (const float*)d_in[2];
  const float* w1  = (const float*)d_in[3];
  const float* b1  = (const float*)d_in[4];
  const float* w2  = (const float*)d_in[5];
  const float* b2  = (const float*)d_in[6];
  const float* lw0 = (const float*)d_in[7];
  const float* lw1 = (const float*)d_in[8];
  const int*   eix = (const int*)d_in[9];

  const int N = in_sizes[0] / 64;
  const int E = in_sizes[9] / 2;
  float* out = (float*)d_out;

  // workspace layout
  char* ws = (char*)d_ws;
  const size_t o_w2t  = 0;                       // 1024 x 64 bf16 = 128 KB
  const size_t o_deg  = 131072;                  // N ints + 1 done int
  const size_t o_done = o_deg + (size_t)N * 4;
  const size_t o_offs = (o_done + 4 + 15) & ~(size_t)15;
  const size_t o_rank = o_offs + (((size_t)(N + 1) * 4 + 15) & ~(size_t)15);
  const size_t o_msg  = (o_rank + (size_t)E * 4 + 255) & ~(size_t)255;
  const size_t need   = o_msg + (size_t)E * 256;
  const int posmode = (ws_size >= need) ? 1 : 0;

  unsigned short* w2t = (unsigned short*)(ws + o_w2t);
  int*   deg  = (int*)(ws + o_deg);
  int*   done = (int*)(ws + o_done);
  int*   offs = (int*)(ws + o_offs);
  int*   rankp = (int*)(ws + o_rank);
  float* msg  = (float*)(ws + o_msg);

  const int eblocks = (E + EPB - 1) / EPB;

  if (posmode) {
    hipMemsetAsync(deg, 0, (size_t)N * 4 + 16, stream);   // deg + done
    prep_kernel<<<dim3(16 + (E + 255) / 256), dim3(256), 0, stream>>>(
        w2, w2t, eix, deg, done, rankp, offs, N, E);
    tfn_edge_kernel<<<dim3(eblocks), dim3(512), 0, stream>>>(
        nf, esh, emb, w1, b1, w2t, b2, eix, rankp, offs, msg, out, E, 1);
    tfn_agg_node_kernel<<<dim3((N + 3) / 4), dim3(256), 0, stream>>>(
        msg, offs, nf, lw0, lw1, out, N);
  } else {
    prep_kernel<<<dim3(16), dim3(256), 0, stream>>>(
        w2, w2t, eix, nullptr, nullptr, nullptr, nullptr, 0, 0);
    hipMemsetAsync(out, 0, (size_t)out_size * sizeof(float), stream);
    tfn_edge_kernel<<<dim3(eblocks), dim3(512), 0, stream>>>(
        nf, esh, emb, w1, b1, w2t, b2, eix, nullptr, nullptr, nullptr, out, E, 0);
    tfn_node_kernel<<<dim3((N + 255) / 256), dim3(256), 0, stream>>>(nf, lw0, lw1, out, N);
  }
}

// Round 13
// 260.000 us; speedup vs baseline: 1.1643x; 1.1643x over previous
//
#include <hip/hip_runtime.h>
#include <hip/hip_bf16.h>
#include <math.h>

#define EPB 64
#define ALPHA 0.17677669529663687f
#define INV_SQRT3 0.57735026918962576f

typedef __attribute__((ext_vector_type(8))) short short8;
typedef __attribute__((ext_vector_type(4))) float f32x4;

__device__ __forceinline__ float silu_f(float x) { return x / (1.0f + __expf(-x)); }

__device__ __forceinline__ unsigned short bf16_rne(float x) {
  unsigned int u = __float_as_uint(x);
  unsigned int r = u + 0x7fffu + ((u >> 16) & 1u);
  return (unsigned short)(r >> 16);
}

__device__ __forceinline__ float bf2f(unsigned short s) {
  return __uint_as_float(((unsigned int)s) << 16);
}

// ---------------------------------------------------------------------------
// Merged prep: blocks 0..15 transpose w2 -> w2t; blocks 16.. CSR count.
// Last-finishing block performs the exclusive scan (done-counter pattern).
// ---------------------------------------------------------------------------
__global__ __launch_bounds__(256) void prep_kernel(const float* __restrict__ w2,
                                                   unsigned short* __restrict__ w2t,
                                                   const int* __restrict__ eidx,
                                                   int* __restrict__ deg,
                                                   int* __restrict__ done,
                                                   int* __restrict__ rank,
                                                   int* __restrict__ offs,
                                                   int N, int E) {
  __shared__ int sums[256];
  __shared__ int s_last;
  const int t = threadIdx.x;

  if (blockIdx.x < 16) {
    __shared__ unsigned short tile[16][260];
    const int k0 = (blockIdx.x & 3) * 16;
    const int c0 = (blockIdx.x >> 2) * 256;
    #pragma unroll
    for (int j = 0; j < 16; ++j)
      tile[j][t] = bf16_rne(w2[(size_t)(k0 + j) * 1024 + c0 + t]);
    __syncthreads();
    union { unsigned short s[16]; uint4 q[2]; } pk;
    #pragma unroll
    for (int j = 0; j < 16; ++j) pk.s[j] = tile[j][t];
    uint4* dst = (uint4*)&w2t[(size_t)(c0 + t) * 64 + k0];
    dst[0] = pk.q[0];
    dst[1] = pk.q[1];
  } else {
    const int e = (blockIdx.x - 16) * 256 + t;
    if (e < E) rank[e] = atomicAdd(&deg[eidx[E + e]], 1);
  }

  // last-block-done: the final block to finish performs the scan
  __threadfence();
  if (t == 0) {
    const int old = atomicAdd(done, 1);
    s_last = (old == (int)gridDim.x - 1) ? 1 : 0;
  }
  __syncthreads();
  if (s_last) {
    __threadfence();
    const int ch = (N + 255) >> 8;
    const int lo = t * ch;
    const int hi = min(lo + ch, N);
    int s = 0;
    for (int i = lo; i < hi; ++i)
      s += __hip_atomic_load(&deg[i], __ATOMIC_RELAXED, __HIP_MEMORY_SCOPE_AGENT);
    sums[t] = s;
    __syncthreads();
    #pragma unroll
    for (int d = 1; d < 256; d <<= 1) {
      int v = (t >= d) ? sums[t - d] : 0;
      __syncthreads();
      sums[t] += v;
      __syncthreads();
    }
    int run = sums[t] - s;
    for (int i = lo; i < hi; ++i) {
      offs[i] = run;
      run += __hip_atomic_load(&deg[i], __ATOMIC_RELAXED, __HIP_MEMORY_SCOPE_AGENT);
    }
    if (lo < N && hi == N) offs[N] = run;
  }
}

// ---------------------------------------------------------------------------
// Edge kernel: 512 threads = 8 waves; wave = (section, half), 2 M-tiles each.
// Same 38.4 KB LDS as R11 but 2x the waves for latency hiding.
// __launch_bounds__(512,2): VGPR cap 256 — NO register forcing. R12's
// (512,6) squeezed VGPR to 40 and spilled ~75 MB (WRITE 94.9 MB); empirical
// law: any bound capping VGPR below ~72 spills and loses.
// ---------------------------------------------------------------------------
__global__ __launch_bounds__(512, 2) void tfn_edge_kernel(
    const float* __restrict__ nf,     // N x 64
    const float* __restrict__ esh,    // E x 4
    const float* __restrict__ emb,    // E x 16
    const float* __restrict__ w1g,    // 16 x 64
    const float* __restrict__ b1g,    // 64
    const unsigned short* __restrict__ w2t, // 1024 x 64 bf16 (transposed)
    const float* __restrict__ b2g,    // 1024
    const int*   __restrict__ eidx,   // 2 x E
    const int*   __restrict__ rank,   // E (posmode)
    const int*   __restrict__ offs,   // N+1 (posmode)
    float* __restrict__ msg,          // E x 64 dst-sorted (posmode)
    float* __restrict__ agg,          // N x 64 pre-zeroed (fallback)
    int E, int posmode)
{
  __shared__ __align__(16) unsigned char smem[38400];
  float* fsT  = (float*)(smem);                            // [16][68] fp32
  float* fbT  = (float*)(smem + 4352);                     // [16][68]
  float* fxvT = (float*)(smem + 8704);                     // 3 planes x [16][68]
  unsigned short* embs = (unsigned short*)(smem + 21760);  // [64][16] bf16
  unsigned short* w1T  = (unsigned short*)(smem + 23808);  // [64][16] bf16 (T)
  unsigned short* t01 = (unsigned short*)(smem);           // overlay: 2 x [64][18]
  unsigned short* t2s = (unsigned short*)(smem + 4608);    // overlay: [64][18]
  unsigned short* t3s = (unsigned short*)(smem + 6912);    // overlay: 3 x [64][18]
  unsigned short* hsm = (unsigned short*)(smem + 25856);   // [64][72] bf16
  unsigned short* b2s = (unsigned short*)(smem + 35072);   // [1024] bf16
  float* shs_l = (float*)(smem + 37120);                   // 64
  float* shv_l = (float*)(smem + 37376);                   // 192
  int*   pos_l = (int*)(smem + 38144);                     // 64

  const int tid = threadIdx.x;
  const int ebase = blockIdx.x * EPB;

  // ---------------- phase 0: stage inputs + factor tables ------------------
  if (tid < 256) {
    const int e = tid >> 2, p = tid & 3;
    int eg = ebase + e; if (eg >= E) eg = E - 1;

    const float4 em = *(const float4*)&emb[(size_t)eg * 16 + p * 4];
    {
      const unsigned int lo = bf16_rne(em.x) | ((unsigned int)bf16_rne(em.y) << 16);
      const unsigned int hi = bf16_rne(em.z) | ((unsigned int)bf16_rne(em.w) << 16);
      *(uint2*)&embs[e * 16 + p * 4] = make_uint2(lo, hi);
    }

    const float4 sh = *(const float4*)&esh[(size_t)eg * 4];
    if (p == 0) {
      shs_l[e] = sh.x;
      shv_l[e * 3 + 0] = sh.y; shv_l[e * 3 + 1] = sh.z; shv_l[e * 3 + 2] = sh.w;
      const int dst = eidx[E + eg];
      pos_l[e] = posmode ? (offs[dst] + rank[eg]) : dst;
    }

    const int src = eidx[eg];
    const float4* row4 = (const float4*)(nf + (size_t)src * 64);
    const float4 xs4 = row4[p];
    const float4 va  = row4[4 + p * 3 + 0];
    const float4 vb  = row4[4 + p * 3 + 1];
    const float4 vc  = row4[4 + p * 3 + 2];
    const float xsr[4] = {xs4.x, xs4.y, xs4.z, xs4.w};
    const float xvf[12] = {va.x, va.y, va.z, va.w, vb.x, vb.y, vb.z, vb.w,
                           vc.x, vc.y, vc.z, vc.w};
    #pragma unroll
    for (int uu = 0; uu < 4; ++uu) {
      const int u = p * 4 + uu;
      const float x0 = xvf[uu * 3 + 0];
      const float x1 = xvf[uu * 3 + 1];
      const float x2 = xvf[uu * 3 + 2];
      fsT[u * 68 + e] = xsr[uu];
      fbT[u * 68 + e] = x0 * sh.y + x1 * sh.z + x2 * sh.w;
      fxvT[0 * 1088 + u * 68 + e] = x0;
      fxvT[1 * 1088 + u * 68 + e] = x1;
      fxvT[2 * 1088 + u * 68 + e] = x2;
    }
  } else {
    const int t2 = tid - 256;
    const int r = t2 >> 4, c4 = (t2 & 15) * 4;
    const float4 wv = *(const float4*)&w1g[r * 64 + c4];
    w1T[(c4 + 0) * 16 + r] = bf16_rne(wv.x);
    w1T[(c4 + 1) * 16 + r] = bf16_rne(wv.y);
    w1T[(c4 + 2) * 16 + r] = bf16_rne(wv.z);
    w1T[(c4 + 3) * 16 + r] = bf16_rne(wv.w);
  }
  {
    const float2 bv = *(const float2*)&b2g[tid * 2];
    *(unsigned int*)&b2s[tid * 2] =
        (unsigned int)bf16_rne(bv.x) | ((unsigned int)bf16_rne(bv.y) << 16);
  }
  __syncthreads();

  const int lane = tid & 63;
  const int wv8  = tid >> 6;           // wave 0..7
  const int sec  = wv8 >> 1;           // W-section 0..3
  const int half = wv8 & 1;            // M-tile half
  const int q = lane >> 4, m = lane & 15;

  union AF { uint4 u4; short8 s8; };

  // ---------------- layer 1 via MFMA: h = silu(emb @ w1 + b1) --------------
  {
    const int et = sec;
    AF ea;
    if (q < 2) ea.u4 = *(const uint4*)&embs[(et * 16 + m) * 16 + q * 8];
    else       ea.u4 = make_uint4(0, 0, 0, 0);
    #pragma unroll
    for (int j = 0; j < 2; ++j) {
      const int ct = half * 2 + j;
      AF wb;
      if (q < 2) wb.u4 = *(const uint4*)&w1T[(ct * 16 + m) * 16 + q * 8];
      else       wb.u4 = make_uint4(0, 0, 0, 0);
      const float b1v = b1g[ct * 16 + m];
      f32x4 c = {b1v, b1v, b1v, b1v};
      c = __builtin_amdgcn_mfma_f32_16x16x32_bf16(ea.s8, wb.s8, c, 0, 0, 0);
      #pragma unroll
      for (int r = 0; r < 4; ++r)
        hsm[(et * 16 + q * 4 + r) * 72 + ct * 16 + m] = bf16_rne(silu_f(c[r]));
    }
  }
  __syncthreads();

  // ---------------- main loop: wave = (section, half), 2 M-tiles -----------
  AF afr[2][2];
  #pragma unroll
  for (int j = 0; j < 2; ++j)
    #pragma unroll
    for (int ks = 0; ks < 2; ++ks)
      afr[j][ks].u4 = *(const uint4*)&hsm[((half * 2 + j) * 16 + m) * 72 + ks * 32 + q * 8];

  const float* ftab = (sec == 3) ? fbT : fsT;
  const uint4* w2tq = (const uint4*)w2t;
  const uint4* bp = w2tq + ((size_t)(sec * 256 + m)) * 8 + q;

  float accA[2][4] = {};
  float accB[2][4] = {};
  float accC[2][4] = {};

  AF b0v, b1v;
  b0v.u4 = bp[0];
  b1v.u4 = bp[4];

  #pragma unroll 2
  for (int u = 0; u < 16; ++u) {
    AF n0, n1;
    if (u < 15) {
      n0.u4 = bp[(u + 1) * 128];
      n1.u4 = bp[(u + 1) * 128 + 4];
    }
    const float b2v = bf2f(b2s[sec * 256 + u * 16 + m]);

    #pragma unroll
    for (int j = 0; j < 2; ++j) {
      const int mt = half * 2 + j;
      f32x4 c = {b2v, b2v, b2v, b2v};
      c = __builtin_amdgcn_mfma_f32_16x16x32_bf16(afr[j][0].s8, b0v.s8, c, 0, 0, 0);
      c = __builtin_amdgcn_mfma_f32_16x16x32_bf16(afr[j][1].s8, b1v.s8, c, 0, 0, 0);

      const int fo = mt * 16 + q * 4;
      if (sec == 2) {
        const float4 f0 = *(const float4*)&fxvT[0 * 1088 + u * 68 + fo];
        const float4 f1 = *(const float4*)&fxvT[1 * 1088 + u * 68 + fo];
        const float4 f2 = *(const float4*)&fxvT[2 * 1088 + u * 68 + fo];
        const float fA[4] = {f0.x, f0.y, f0.z, f0.w};
        const float fB[4] = {f1.x, f1.y, f1.z, f1.w};
        const float fC[4] = {f2.x, f2.y, f2.z, f2.w};
        #pragma unroll
        for (int r = 0; r < 4; ++r) {
          accA[j][r] = fmaf(fA[r], c[r], accA[j][r]);
          accB[j][r] = fmaf(fB[r], c[r], accB[j][r]);
          accC[j][r] = fmaf(fC[r], c[r], accC[j][r]);
        }
      } else {
        const float4 f = *(const float4*)&ftab[u * 68 + fo];
        const float fA[4] = {f.x, f.y, f.z, f.w};
        #pragma unroll
        for (int r = 0; r < 4; ++r)
          accA[j][r] = fmaf(fA[r], c[r], accA[j][r]);
      }
    }
    if (u < 15) { b0v = n0; b1v = n1; }
  }

  __syncthreads();   // factor tables dead; t-overlay may now be written

  // ---------------- flush wave partials to LDS (bf16, stride 18) -----------
  #pragma unroll
  for (int j = 0; j < 2; ++j)
    #pragma unroll
    for (int r = 0; r < 4; ++r) {
      const int e = (half * 2 + j) * 16 + q * 4 + r;
      if (sec == 0)      t01[e * 18 + m]        = bf16_rne(accA[j][r] * shs_l[e]);
      else if (sec == 1) t2s[e * 18 + m]        = bf16_rne(accA[j][r]);
      else if (sec == 3) t01[1152 + e * 18 + m] = bf16_rne(accA[j][r]);
      else {
        const float s = shs_l[e];
        t3s[0 * 1152 + e * 18 + m] = bf16_rne(accA[j][r] * s);
        t3s[1 * 1152 + e * 18 + m] = bf16_rne(accB[j][r] * s);
        t3s[2 * 1152 + e * 18 + m] = bf16_rne(accC[j][r] * s);
      }
    }
  __syncthreads();

  // ---------------- combine + emit, coalesced per-edge rows ----------------
  {
    const int lc = lane;
    const int cc = lc - 16;
    const int v  = cc / 3;
    const int i3 = cc - v * 3;
    #pragma unroll 1
    for (int t8 = 0; t8 < 8; ++t8) {
      const int e = wv8 * 8 + t8;
      if (ebase + e < E) {
        float val;
        if (lc < 16) {
          val = ALPHA * (bf2f(t01[e * 18 + lc]) + INV_SQRT3 * bf2f(t01[1152 + e * 18 + lc]));
        } else {
          val = ALPHA * (bf2f(t2s[e * 18 + v]) * shv_l[e * 3 + i3] +
                         bf2f(t3s[i3 * 1152 + e * 18 + v]));
        }
        if (posmode) msg[(size_t)pos_l[e] * 64 + lc] = val;
        else         atomicAdd(&agg[(size_t)pos_l[e] * 64 + lc], val);
      }
    }
  }
}

// ---------------------------------------------------------------------------
// Fused aggregation + node transform (R9-proven, unchanged). Block = 4 nodes.
// ---------------------------------------------------------------------------
__global__ __launch_bounds__(256) void tfn_agg_node_kernel(
    const float* __restrict__ msg, const int* __restrict__ offs,
    const float* __restrict__ nf, const float* __restrict__ lw0,
    const float* __restrict__ lw1, float* __restrict__ out, int N)
{
  __shared__ float ag[4 * 68];
  __shared__ float w0s[256], w1s[256];
  const int t = threadIdx.x;
  w0s[t] = lw0[t];
  w1s[t] = lw1[t];

  const int n0 = blockIdx.x * 4;
  {
    const int w = t >> 6, lane = t & 63;
    const int rq = lane >> 4, cl = lane & 15;
    const int n = n0 + w;
    if (n < N) {
      const int s = offs[n], e = offs[n + 1];
      float a0 = 0.0f, a1 = 0.0f, a2 = 0.0f, a3 = 0.0f;
      for (int j = s + rq; j < e; j += 4) {
        const float4 v = *(const float4*)&msg[(size_t)j * 64 + cl * 4];
        a0 += v.x; a1 += v.y; a2 += v.z; a3 += v.w;
      }
      a0 += __shfl_xor(a0, 16); a0 += __shfl_xor(a0, 32);
      a1 += __shfl_xor(a1, 16); a1 += __shfl_xor(a1, 32);
      a2 += __shfl_xor(a2, 16); a2 += __shfl_xor(a2, 32);
      a3 += __shfl_xor(a3, 16); a3 += __shfl_xor(a3, 32);
      if (rq == 0) *(float4*)&ag[w * 68 + cl * 4] = make_float4(a0, a1, a2, a3);
    }
  }
  __syncthreads();
  {
    const int node = t >> 6, c = t & 63;
    const int n = n0 + node;
    if (n >= N) return;
    const float* a = &ag[node * 68];
    float val;
    if (c < 16) {
      float accv = 0.0f;
      #pragma unroll
      for (int u = 0; u < 16; ++u) accv = fmaf(a[u], w0s[u * 16 + c], accv);
      const float ts = 0.25f * accv;
      const float ns = fabsf(ts);
      const float g = (ns / (1.0f + __expf(-ns))) / (ns + 1e-8f);
      val = ts * g;
    } else {
      const int cc = c - 16;
      const int v = cc / 3, i = cc - v * 3;
      float a0 = 0.0f, a1 = 0.0f, a2 = 0.0f;
      #pragma unroll
      for (int u = 0; u < 16; ++u) {
        const float w = w1s[u * 16 + v];
        a0 = fmaf(a[16 + u * 3 + 0], w, a0);
        a1 = fmaf(a[16 + u * 3 + 1], w, a1);
        a2 = fmaf(a[16 + u * 3 + 2], w, a2);
      }
      a0 *= 0.25f; a1 *= 0.25f; a2 *= 0.25f;
      const float nv = sqrtf(a0 * a0 + a1 * a1 + a2 * a2);
      const float g = (nv / (1.0f + __expf(-nv))) / (nv + 1e-8f);
      val = ((i == 0) ? a0 : (i == 1) ? a1 : a2) * g;
    }
    out[(size_t)n * 64 + c] = nf[(size_t)n * 64 + c] + val;
  }
}

// ---------------------------------------------------------------------------
// Fallback node kernel (atomic path only).
// ---------------------------------------------------------------------------
__global__ __launch_bounds__(256) void tfn_node_kernel(
    const float* __restrict__ nf,
    const float* __restrict__ lw0,
    const float* __restrict__ lw1,
    float* __restrict__ out, int N)
{
  __shared__ float w0s[256], w1s[256];
  const int tid = threadIdx.x;
  w0s[tid] = lw0[tid];
  w1s[tid] = lw1[tid];
  __syncthreads();

  const int n = blockIdx.x * 256 + tid;
  if (n >= N) return;

  float* rowp = out + (size_t)n * 64;
  float as[16], av[16][3];
  #pragma unroll
  for (int u = 0; u < 16; ++u) as[u] = rowp[u];
  #pragma unroll
  for (int u = 0; u < 16; ++u) {
    av[u][0] = rowp[16 + u * 3 + 0];
    av[u][1] = rowp[16 + u * 3 + 1];
    av[u][2] = rowp[16 + u * 3 + 2];
  }
  const float* nfr = nf + (size_t)n * 64;
  float res[64];

  #pragma unroll
  for (int v = 0; v < 16; ++v) {
    float acc = 0.0f;
    #pragma unroll
    for (int u = 0; u < 16; ++u) acc = fmaf(as[u], w0s[u * 16 + v], acc);
    const float ts = 0.25f * acc;
    const float ns = fabsf(ts);
    const float g = (ns / (1.0f + __expf(-ns))) / (ns + 1e-8f);
    res[v] = nfr[v] + ts * g;
  }
  #pragma unroll
  for (int v = 0; v < 16; ++v) {
    float a0 = 0.0f, a1 = 0.0f, a2 = 0.0f;
    #pragma unroll
    for (int u = 0; u < 16; ++u) {
      const float w = w1s[u * 16 + v];
      a0 = fmaf(av[u][0], w, a0);
      a1 = fmaf(av[u][1], w, a1);
      a2 = fmaf(av[u][2], w, a2);
    }
    a0 *= 0.25f; a1 *= 0.25f; a2 *= 0.25f;
    const float nv = sqrtf(a0 * a0 + a1 * a1 + a2 * a2);
    const float g = (nv / (1.0f + __expf(-nv))) / (nv + 1e-8f);
    res[16 + v * 3 + 0] = nfr[16 + v * 3 + 0] + a0 * g;
    res[16 + v * 3 + 1] = nfr[16 + v * 3 + 1] + a1 * g;
    res[16 + v * 3 + 2] = nfr[16 + v * 3 + 2] + a2 * g;
  }
  #pragma unroll
  for (int o = 0; o < 64; o += 4) {
    *(float4*)&rowp[o] = make_float4(res[o], res[o + 1], res[o + 2], res[o + 3]);
  }
}

extern "C" void kernel_launch(void* const* d_in, const int* in_sizes, int n_in,
                              void* d_out, int out_size, void* d_ws, size_t ws_size,
                              hipStream_t stream) {
  const float* nf  = (const float*)d_in[0];
  const float* esh = (const float*)d_in[1];
  const float* emb = (const float*)d_in[2];
  const float* w1  = (const float*)d_in[3];
  const float* b1  = (const float*)d_in[4];
  const float* w2  = (const float*)d_in[5];
  const float* b2  = (const float*)d_in[6];
  const float* lw0 = (const float*)d_in[7];
  const float* lw1 = (const float*)d_in[8];
  const int*   eix = (const int*)d_in[9];

  const int N = in_sizes[0] / 64;
  const int E = in_sizes[9] / 2;
  float* out = (float*)d_out;

  // workspace layout
  char* ws = (char*)d_ws;
  const size_t o_w2t  = 0;                       // 1024 x 64 bf16 = 128 KB
  const size_t o_deg  = 131072;                  // N ints + 1 done int
  const size_t o_done = o_deg + (size_t)N * 4;
  const size_t o_offs = (o_done + 4 + 15) & ~(size_t)15;
  const size_t o_rank = o_offs + (((size_t)(N + 1) * 4 + 15) & ~(size_t)15);
  const size_t o_msg  = (o_rank + (size_t)E * 4 + 255) & ~(size_t)255;
  const size_t need   = o_msg + (size_t)E * 256;
  const int posmode = (ws_size >= need) ? 1 : 0;

  unsigned short* w2t = (unsigned short*)(ws + o_w2t);
  int*   deg  = (int*)(ws + o_deg);
  int*   done = (int*)(ws + o_done);
  int*   offs = (int*)(ws + o_offs);
  int*   rankp = (int*)(ws + o_rank);
  float* msg  = (float*)(ws + o_msg);

  const int eblocks = (E + EPB - 1) / EPB;

  if (posmode) {
    hipMemsetAsync(deg, 0, (size_t)N * 4 + 16, stream);   // deg + done
    prep_kernel<<<dim3(16 + (E + 255) / 256), dim3(256), 0, stream>>>(
        w2, w2t, eix, deg, done, rankp, offs, N, E);
    tfn_edge_kernel<<<dim3(eblocks), dim3(512), 0, stream>>>(
        nf, esh, emb, w1, b1, w2t, b2, eix, rankp, offs, msg, out, E, 1);
    tfn_agg_node_kernel<<<dim3((N + 3) / 4), dim3(256), 0, stream>>>(
        msg, offs, nf, lw0, lw1, out, N);
  } else {
    prep_kernel<<<dim3(16), dim3(256), 0, stream>>>(
        w2, w2t, eix, nullptr, nullptr, nullptr, nullptr, 0, 0);
    hipMemsetAsync(out, 0, (size_t)out_size * sizeof(float), stream);
    tfn_edge_kernel<<<dim3(eblocks), dim3(512), 0, stream>>>(
        nf, esh, emb, w1, b1, w2t, b2, eix, nullptr, nullptr, nullptr, out, E, 0);
    tfn_node_kernel<<<dim3((N + 255) / 256), dim3(256), 0, stream>>>(nf, lw0, lw1, out, N);
  }
}

// Round 14
// 178.522 us; speedup vs baseline: 1.6957x; 1.4564x over previous
//
#include <hip/hip_runtime.h>
#include <hip/hip_bf16.h>
#include <math.h>

#define EPB 64
#define ALPHA 0.17677669529663687f
#define INV_SQRT3 0.57735026918962576f

typedef __attribute__((ext_vector_type(8))) short short8;
typedef __attribute__((ext_vector_type(4))) float f32x4;

__device__ __forceinline__ float silu_f(float x) { return x / (1.0f + __expf(-x)); }

__device__ __forceinline__ unsigned short bf16_rne(float x) {
  unsigned int u = __float_as_uint(x);
  unsigned int r = u + 0x7fffu + ((u >> 16) & 1u);
  return (unsigned short)(r >> 16);
}

__device__ __forceinline__ float bf2f(unsigned short s) {
  return __uint_as_float(((unsigned int)s) << 16);
}

// ---------------------------------------------------------------------------
// Merged prep: blocks 0..15 transpose w2 -> w2t (R3-proven code);
// blocks 16.. do the CSR count (rank = atomicAdd(deg[dst])).
// (R12/R13's done-counter scan merge cost ~55 us of tail — reverted.)
// ---------------------------------------------------------------------------
__global__ __launch_bounds__(256) void prep_kernel(const float* __restrict__ w2,
                                                   unsigned short* __restrict__ w2t,
                                                   const int* __restrict__ eidx,
                                                   int* __restrict__ deg,
                                                   int* __restrict__ rank, int E) {
  if (blockIdx.x < 16) {
    __shared__ unsigned short tile[16][260];
    const int t = threadIdx.x;
    const int k0 = (blockIdx.x & 3) * 16;
    const int c0 = (blockIdx.x >> 2) * 256;
    #pragma unroll
    for (int j = 0; j < 16; ++j)
      tile[j][t] = bf16_rne(w2[(size_t)(k0 + j) * 1024 + c0 + t]);
    __syncthreads();
    union { unsigned short s[16]; uint4 q[2]; } pk;
    #pragma unroll
    for (int j = 0; j < 16; ++j) pk.s[j] = tile[j][t];
    uint4* dst = (uint4*)&w2t[(size_t)(c0 + t) * 64 + k0];
    dst[0] = pk.q[0];
    dst[1] = pk.q[1];
  } else {
    const int e = (blockIdx.x - 16) * 256 + threadIdx.x;
    if (e < E) rank[e] = atomicAdd(&deg[eidx[E + e]], 1);
  }
}

// 1024-thread single-block exclusive prefix sum over N degrees -> offs[0..N].
__global__ __launch_bounds__(1024) void scan_kernel(const int* __restrict__ deg,
                                                    int* __restrict__ offs, int N) {
  __shared__ int sums[1024];
  const int t = threadIdx.x;
  const int ch = (N + 1023) >> 10;
  const int lo = t * ch;
  const int hi = min(lo + ch, N);
  int s = 0;
  for (int i = lo; i < hi; ++i) s += deg[i];
  sums[t] = s;
  __syncthreads();
  #pragma unroll
  for (int d = 1; d < 1024; d <<= 1) {
    int v = (t >= d) ? sums[t - d] : 0;
    __syncthreads();
    sums[t] += v;
    __syncthreads();
  }
  int run = sums[t] - s;
  for (int i = lo; i < hi; ++i) { offs[i] = run; run += deg[i]; }
  if (lo < N && hi == N) offs[N] = run;
}

// ---------------------------------------------------------------------------
// Edge kernel (R11-proven structure). Wave = one W-section (B-reuse x4).
// fp32 factor tables overlaid by bf16 t-buffers. Layer-1 via MFMA. b2 bf16,
// folded into MFMA C-init. LDS 38400 B. msg emitted in bf16 (halves WRITE).
// NOTE: any __launch_bounds__ that caps VGPR below ~72 spills (R7/R8/R12);
// (256,3) is the proven no-spill point. 512-thread variant (R13) was slower
// despite 41% occupancy — B-reuse halving costs more than waves buy.
// ---------------------------------------------------------------------------
__global__ __launch_bounds__(256, 3) void tfn_edge_kernel(
    const float* __restrict__ nf,     // N x 64
    const float* __restrict__ esh,    // E x 4
    const float* __restrict__ emb,    // E x 16
    const float* __restrict__ w1g,    // 16 x 64
    const float* __restrict__ b1g,    // 64
    const unsigned short* __restrict__ w2t, // 1024 x 64 bf16 (transposed)
    const float* __restrict__ b2g,    // 1024
    const int*   __restrict__ eidx,   // 2 x E
    const int*   __restrict__ rank,   // E (posmode)
    const int*   __restrict__ offs,   // N+1 (posmode)
    unsigned short* __restrict__ msg, // E x 64 bf16 dst-sorted (posmode)
    float* __restrict__ agg,          // N x 64 pre-zeroed (fallback)
    int E, int posmode)
{
  __shared__ __align__(16) unsigned char smem[38400];
  float* fsT  = (float*)(smem);                            // [16][68] fp32
  float* fbT  = (float*)(smem + 4352);                     // [16][68]
  float* fxvT = (float*)(smem + 8704);                     // 3 planes x [16][68]
  unsigned short* embs = (unsigned short*)(smem + 21760);  // [64][16] bf16
  unsigned short* w1T  = (unsigned short*)(smem + 23808);  // [64][16] bf16 (T)
  unsigned short* t01 = (unsigned short*)(smem);           // overlay: 2 x [64][18]
  unsigned short* t2s = (unsigned short*)(smem + 4608);    // overlay: [64][18]
  unsigned short* t3s = (unsigned short*)(smem + 6912);    // overlay: 3 x [64][18]
  unsigned short* hsm = (unsigned short*)(smem + 25856);   // [64][72] bf16
  unsigned short* b2s = (unsigned short*)(smem + 35072);   // [1024] bf16
  float* shs_l = (float*)(smem + 37120);                   // 64
  float* shv_l = (float*)(smem + 37376);                   // 192
  int*   pos_l = (int*)(smem + 38144);                     // 64

  const int tid = threadIdx.x;
  const int ebase = blockIdx.x * EPB;

  // ---------------- phase 0: stage inputs + factor tables ------------------
  {
    const int e = tid >> 2, p = tid & 3;
    int eg = ebase + e; if (eg >= E) eg = E - 1;

    const float4 em = *(const float4*)&emb[(size_t)eg * 16 + p * 4];
    {
      const unsigned int lo = bf16_rne(em.x) | ((unsigned int)bf16_rne(em.y) << 16);
      const unsigned int hi = bf16_rne(em.z) | ((unsigned int)bf16_rne(em.w) << 16);
      *(uint2*)&embs[e * 16 + p * 4] = make_uint2(lo, hi);
    }

    const float4 sh = *(const float4*)&esh[(size_t)eg * 4];
    if (p == 0) {
      shs_l[e] = sh.x;
      shv_l[e * 3 + 0] = sh.y; shv_l[e * 3 + 1] = sh.z; shv_l[e * 3 + 2] = sh.w;
      const int dst = eidx[E + eg];
      pos_l[e] = posmode ? (offs[dst] + rank[eg]) : dst;
    }

    const int src = eidx[eg];
    const float4* row4 = (const float4*)(nf + (size_t)src * 64);
    const float4 xs4 = row4[p];
    const float4 va  = row4[4 + p * 3 + 0];
    const float4 vb  = row4[4 + p * 3 + 1];
    const float4 vc  = row4[4 + p * 3 + 2];
    const float xsr[4] = {xs4.x, xs4.y, xs4.z, xs4.w};
    const float xvf[12] = {va.x, va.y, va.z, va.w, vb.x, vb.y, vb.z, vb.w,
                           vc.x, vc.y, vc.z, vc.w};
    #pragma unroll
    for (int uu = 0; uu < 4; ++uu) {
      const int u = p * 4 + uu;
      const float x0 = xvf[uu * 3 + 0];
      const float x1 = xvf[uu * 3 + 1];
      const float x2 = xvf[uu * 3 + 2];
      fsT[u * 68 + e] = xsr[uu];
      fbT[u * 68 + e] = x0 * sh.y + x1 * sh.z + x2 * sh.w;
      fxvT[0 * 1088 + u * 68 + e] = x0;
      fxvT[1 * 1088 + u * 68 + e] = x1;
      fxvT[2 * 1088 + u * 68 + e] = x2;
    }
  }
  {
    const int r = tid >> 4, c4 = (tid & 15) * 4;
    const float4 wv = *(const float4*)&w1g[r * 64 + c4];
    w1T[(c4 + 0) * 16 + r] = bf16_rne(wv.x);
    w1T[(c4 + 1) * 16 + r] = bf16_rne(wv.y);
    w1T[(c4 + 2) * 16 + r] = bf16_rne(wv.z);
    w1T[(c4 + 3) * 16 + r] = bf16_rne(wv.w);
  }
  {
    const float4 bv = *(const float4*)&b2g[tid * 4];
    const unsigned int lo = bf16_rne(bv.x) | ((unsigned int)bf16_rne(bv.y) << 16);
    const unsigned int hi = bf16_rne(bv.z) | ((unsigned int)bf16_rne(bv.w) << 16);
    *(uint2*)&b2s[tid * 4] = make_uint2(lo, hi);
  }
  __syncthreads();

  const int lane = tid & 63;
  const int sec  = tid >> 6;           // wave-uniform
  const int q = lane >> 4, m = lane & 15;

  union AF { uint4 u4; short8 s8; };

  // ---------------- layer 1 via MFMA: h = silu(emb @ w1 + b1) --------------
  {
    AF ea;
    if (q < 2) ea.u4 = *(const uint4*)&embs[(sec * 16 + m) * 16 + q * 8];
    else       ea.u4 = make_uint4(0, 0, 0, 0);
    #pragma unroll
    for (int ct = 0; ct < 4; ++ct) {
      AF wb;
      if (q < 2) wb.u4 = *(const uint4*)&w1T[(ct * 16 + m) * 16 + q * 8];
      else       wb.u4 = make_uint4(0, 0, 0, 0);
      const float b1v = b1g[ct * 16 + m];
      f32x4 c = {b1v, b1v, b1v, b1v};
      c = __builtin_amdgcn_mfma_f32_16x16x32_bf16(ea.s8, wb.s8, c, 0, 0, 0);
      #pragma unroll
      for (int r = 0; r < 4; ++r)
        hsm[(sec * 16 + q * 4 + r) * 72 + ct * 16 + m] = bf16_rne(silu_f(c[r]));
    }
  }
  __syncthreads();

  // ---------------- main loop: wave = section, 4 M-tiles, B prefetch -------
  AF afr[4][2];
  #pragma unroll
  for (int mt = 0; mt < 4; ++mt)
    #pragma unroll
    for (int ks = 0; ks < 2; ++ks)
      afr[mt][ks].u4 = *(const uint4*)&hsm[(mt * 16 + m) * 72 + ks * 32 + q * 8];

  const float* ftab = (sec == 3) ? fbT : fsT;
  const uint4* w2tq = (const uint4*)w2t;
  const uint4* bp = w2tq + ((size_t)(sec * 256 + m)) * 8 + q;

  float accA[4][4] = {};
  float accB[4][4] = {};
  float accC[4][4] = {};

  AF b0v, b1v;
  b0v.u4 = bp[0];
  b1v.u4 = bp[4];

  #pragma unroll 2
  for (int u = 0; u < 16; ++u) {
    AF n0, n1;
    if (u < 15) {
      n0.u4 = bp[(u + 1) * 128];
      n1.u4 = bp[(u + 1) * 128 + 4];
    }
    const float b2v = bf2f(b2s[sec * 256 + u * 16 + m]);

    #pragma unroll
    for (int mt = 0; mt < 4; ++mt) {
      f32x4 c = {b2v, b2v, b2v, b2v};
      c = __builtin_amdgcn_mfma_f32_16x16x32_bf16(afr[mt][0].s8, b0v.s8, c, 0, 0, 0);
      c = __builtin_amdgcn_mfma_f32_16x16x32_bf16(afr[mt][1].s8, b1v.s8, c, 0, 0, 0);

      const int fo = mt * 16 + q * 4;
      if (sec == 2) {
        const float4 f0 = *(const float4*)&fxvT[0 * 1088 + u * 68 + fo];
        const float4 f1 = *(const float4*)&fxvT[1 * 1088 + u * 68 + fo];
        const float4 f2 = *(const float4*)&fxvT[2 * 1088 + u * 68 + fo];
        const float fA[4] = {f0.x, f0.y, f0.z, f0.w};
        const float fB[4] = {f1.x, f1.y, f1.z, f1.w};
        const float fC[4] = {f2.x, f2.y, f2.z, f2.w};
        #pragma unroll
        for (int r = 0; r < 4; ++r) {
          accA[mt][r] = fmaf(fA[r], c[r], accA[mt][r]);
          accB[mt][r] = fmaf(fB[r], c[r], accB[mt][r]);
          accC[mt][r] = fmaf(fC[r], c[r], accC[mt][r]);
        }
      } else {
        const float4 f = *(const float4*)&ftab[u * 68 + fo];
        const float fA[4] = {f.x, f.y, f.z, f.w};
        #pragma unroll
        for (int r = 0; r < 4; ++r)
          accA[mt][r] = fmaf(fA[r], c[r], accA[mt][r]);
      }
    }
    if (u < 15) { b0v = n0; b1v = n1; }
  }

  __syncthreads();   // factor tables dead; t-overlay may now be written

  // ---------------- flush wave partials to LDS (bf16, stride 18) -----------
  #pragma unroll
  for (int mt = 0; mt < 4; ++mt)
    #pragma unroll
    for (int r = 0; r < 4; ++r) {
      const int e = mt * 16 + q * 4 + r;
      if (sec == 0)      t01[e * 18 + m]        = bf16_rne(accA[mt][r] * shs_l[e]);
      else if (sec == 1) t2s[e * 18 + m]        = bf16_rne(accA[mt][r]);
      else if (sec == 3) t01[1152 + e * 18 + m] = bf16_rne(accA[mt][r]);
      else {
        const float s = shs_l[e];
        t3s[0 * 1152 + e * 18 + m] = bf16_rne(accA[mt][r] * s);
        t3s[1 * 1152 + e * 18 + m] = bf16_rne(accB[mt][r] * s);
        t3s[2 * 1152 + e * 18 + m] = bf16_rne(accC[mt][r] * s);
      }
    }
  __syncthreads();

  // ---------------- combine + emit (bf16 msg), coalesced per-edge rows -----
  {
    const int w = tid >> 6, lc = tid & 63;
    const int cc = lc - 16;
    const int v  = cc / 3;
    const int i3 = cc - v * 3;
    #pragma unroll 1
    for (int t8 = 0; t8 < 16; ++t8) {
      const int e = w * 16 + t8;
      if (ebase + e < E) {
        float val;
        if (lc < 16) {
          val = ALPHA * (bf2f(t01[e * 18 + lc]) + INV_SQRT3 * bf2f(t01[1152 + e * 18 + lc]));
        } else {
          val = ALPHA * (bf2f(t2s[e * 18 + v]) * shv_l[e * 3 + i3] +
                         bf2f(t3s[i3 * 1152 + e * 18 + v]));
        }
        if (posmode) msg[(size_t)pos_l[e] * 64 + lc] = bf16_rne(val);
        else         atomicAdd(&agg[(size_t)pos_l[e] * 64 + lc], val);
      }
    }
  }
}

// ---------------------------------------------------------------------------
// Fused aggregation + node transform. Block = 4 nodes. msg is bf16:
// lane cl reads uint2 (4 bf16 channels) per edge row; rq strides 4 edges;
// shfl-xor reduce across row-groups as before.
// ---------------------------------------------------------------------------
__global__ __launch_bounds__(256) void tfn_agg_node_kernel(
    const unsigned short* __restrict__ msg, const int* __restrict__ offs,
    const float* __restrict__ nf, const float* __restrict__ lw0,
    const float* __restrict__ lw1, float* __restrict__ out, int N)
{
  __shared__ float ag[4 * 68];
  __shared__ float w0s[256], w1s[256];
  const int t = threadIdx.x;
  w0s[t] = lw0[t];
  w1s[t] = lw1[t];

  const int n0 = blockIdx.x * 4;
  {
    const int w = t >> 6, lane = t & 63;
    const int rq = lane >> 4, cl = lane & 15;
    const int n = n0 + w;
    if (n < N) {
      const int s = offs[n], e = offs[n + 1];
      float a0 = 0.0f, a1 = 0.0f, a2 = 0.0f, a3 = 0.0f;
      for (int j = s + rq; j < e; j += 4) {
        const uint2 v = *(const uint2*)&msg[(size_t)j * 64 + cl * 4];
        a0 += __uint_as_float(v.x << 16);
        a1 += __uint_as_float(v.x & 0xffff0000u);
        a2 += __uint_as_float(v.y << 16);
        a3 += __uint_as_float(v.y & 0xffff0000u);
      }
      a0 += __shfl_xor(a0, 16); a0 += __shfl_xor(a0, 32);
      a1 += __shfl_xor(a1, 16); a1 += __shfl_xor(a1, 32);
      a2 += __shfl_xor(a2, 16); a2 += __shfl_xor(a2, 32);
      a3 += __shfl_xor(a3, 16); a3 += __shfl_xor(a3, 32);
      if (rq == 0) *(float4*)&ag[w * 68 + cl * 4] = make_float4(a0, a1, a2, a3);
    }
  }
  __syncthreads();
  {
    const int node = t >> 6, c = t & 63;
    const int n = n0 + node;
    if (n >= N) return;
    const float* a = &ag[node * 68];
    float val;
    if (c < 16) {
      float accv = 0.0f;
      #pragma unroll
      for (int u = 0; u < 16; ++u) accv = fmaf(a[u], w0s[u * 16 + c], accv);
      const float ts = 0.25f * accv;
      const float ns = fabsf(ts);
      const float g = (ns / (1.0f + __expf(-ns))) / (ns + 1e-8f);
      val = ts * g;
    } else {
      const int cc = c - 16;
      const int v = cc / 3, i = cc - v * 3;
      float a0 = 0.0f, a1 = 0.0f, a2 = 0.0f;
      #pragma unroll
      for (int u = 0; u < 16; ++u) {
        const float w = w1s[u * 16 + v];
        a0 = fmaf(a[16 + u * 3 + 0], w, a0);
        a1 = fmaf(a[16 + u * 3 + 1], w, a1);
        a2 = fmaf(a[16 + u * 3 + 2], w, a2);
      }
      a0 *= 0.25f; a1 *= 0.25f; a2 *= 0.25f;
      const float nv = sqrtf(a0 * a0 + a1 * a1 + a2 * a2);
      const float g = (nv / (1.0f + __expf(-nv))) / (nv + 1e-8f);
      val = ((i == 0) ? a0 : (i == 1) ? a1 : a2) * g;
    }
    out[(size_t)n * 64 + c] = nf[(size_t)n * 64 + c] + val;
  }
}

// ---------------------------------------------------------------------------
// Fallback node kernel (atomic path only).
// ---------------------------------------------------------------------------
__global__ __launch_bounds__(256) void tfn_node_kernel(
    const float* __restrict__ nf,
    const float* __restrict__ lw0,
    const float* __restrict__ lw1,
    float* __restrict__ out, int N)
{
  __shared__ float w0s[256], w1s[256];
  const int tid = threadIdx.x;
  w0s[tid] = lw0[tid];
  w1s[tid] = lw1[tid];
  __syncthreads();

  const int n = blockIdx.x * 256 + tid;
  if (n >= N) return;

  float* rowp = out + (size_t)n * 64;
  float as[16], av[16][3];
  #pragma unroll
  for (int u = 0; u < 16; ++u) as[u] = rowp[u];
  #pragma unroll
  for (int u = 0; u < 16; ++u) {
    av[u][0] = rowp[16 + u * 3 + 0];
    av[u][1] = rowp[16 + u * 3 + 1];
    av[u][2] = rowp[16 + u * 3 + 2];
  }
  const float* nfr = nf + (size_t)n * 64;
  float res[64];

  #pragma unroll
  for (int v = 0; v < 16; ++v) {
    float acc = 0.0f;
    #pragma unroll
    for (int u = 0; u < 16; ++u) acc = fmaf(as[u], w0s[u * 16 + v], acc);
    const float ts = 0.25f * acc;
    const float ns = fabsf(ts);
    const float g = (ns / (1.0f + __expf(-ns))) / (ns + 1e-8f);
    res[v] = nfr[v] + ts * g;
  }
  #pragma unroll
  for (int v = 0; v < 16; ++v) {
    float a0 = 0.0f, a1 = 0.0f, a2 = 0.0f;
    #pragma unroll
    for (int u = 0; u < 16; ++u) {
      const float w = w1s[u * 16 + v];
      a0 = fmaf(av[u][0], w, a0);
      a1 = fmaf(av[u][1], w, a1);
      a2 = fmaf(av[u][2], w, a2);
    }
    a0 *= 0.25f; a1 *= 0.25f; a2 *= 0.25f;
    const float nv = sqrtf(a0 * a0 + a1 * a1 + a2 * a2);
    const float g = (nv / (1.0f + __expf(-nv))) / (nv + 1e-8f);
    res[16 + v * 3 + 0] = nfr[16 + v * 3 + 0] + a0 * g;
    res[16 + v * 3 + 1] = nfr[16 + v * 3 + 1] + a1 * g;
    res[16 + v * 3 + 2] = nfr[16 + v * 3 + 2] + a2 * g;
  }
  #pragma unroll
  for (int o = 0; o < 64; o += 4) {
    *(float4*)&rowp[o] = make_float4(res[o], res[o + 1], res[o + 2], res[o + 3]);
  }
}

extern "C" void kernel_launch(void* const* d_in, const int* in_sizes, int n_in,
                              void* d_out, int out_size, void* d_ws, size_t ws_size,
                              hipStream_t stream) {
  const float* nf  = (const float*)d_in[0];
  const float* esh = (const float*)d_in[1];
  const float* emb = (const float*)d_in[2];
  const float* w1  = (const float*)d_in[3];
  const float* b1  = (const float*)d_in[4];
  const float* w2  = (const float*)d_in[5];
  const float* b2  = (const float*)d_in[6];
  const float* lw0 = (const float*)d_in[7];
  const float* lw1 = (const float*)d_in[8];
  const int*   eix = (const int*)d_in[9];

  const int N = in_sizes[0] / 64;
  const int E = in_sizes[9] / 2;
  float* out = (float*)d_out;

  // workspace layout
  char* ws = (char*)d_ws;
  const size_t o_w2t  = 0;                       // 1024 x 64 bf16 = 128 KB
  const size_t o_deg  = 131072;
  const size_t o_offs = o_deg  + (((size_t)N * 4 + 15) & ~(size_t)15);
  const size_t o_rank = o_offs + (((size_t)(N + 1) * 4 + 15) & ~(size_t)15);
  const size_t o_msg  = (o_rank + (size_t)E * 4 + 255) & ~(size_t)255;
  const size_t need   = o_msg + (size_t)E * 128;   // bf16 msg
  const int posmode = (ws_size >= need) ? 1 : 0;

  unsigned short* w2t = (unsigned short*)(ws + o_w2t);
  int*   deg  = (int*)(ws + o_deg);
  int*   offs = (int*)(ws + o_offs);
  int*   rankp = (int*)(ws + o_rank);
  unsigned short* msg = (unsigned short*)(ws + o_msg);

  const int eblocks = (E + EPB - 1) / EPB;

  if (posmode) {
    hipMemsetAsync(deg, 0, (size_t)N * 4, stream);
    prep_kernel<<<dim3(16 + (E + 255) / 256), dim3(256), 0, stream>>>(
        w2, w2t, eix, deg, rankp, E);
    scan_kernel<<<dim3(1), dim3(1024), 0, stream>>>(deg, offs, N);
    tfn_edge_kernel<<<dim3(eblocks), dim3(256), 0, stream>>>(
        nf, esh, emb, w1, b1, w2t, b2, eix, rankp, offs, msg, out, E, 1);
    tfn_agg_node_kernel<<<dim3((N + 3) / 4), dim3(256), 0, stream>>>(
        msg, offs, nf, lw0, lw1, out, N);
  } else {
    prep_kernel<<<dim3(16), dim3(256), 0, stream>>>(w2, w2t, eix, nullptr, nullptr, 0);
    hipMemsetAsync(out, 0, (size_t)out_size * sizeof(float), stream);
    tfn_edge_kernel<<<dim3(eblocks), dim3(256), 0, stream>>>(
        nf, esh, emb, w1, b1, w2t, b2, eix, nullptr, nullptr, nullptr, out, E, 0);
    tfn_node_kernel<<<dim3((N + 255) / 256), dim3(256), 0, stream>>>(nf, lw0, lw1, out, N);
  }
}